// Round 12
// baseline (1515.455 us; speedup 1.0000x reference)
//
#include <hip/hip_runtime.h>
#include <hip/hip_bf16.h>
#include <math.h>

#define LQ 512
#define HH 512
#define EE 300
#define WW 20
#define G4 2048
#define EPSF 1e-8f
#define RB 32   // blocks per LSTM in recurrence
#define JPB 16  // j (h-elements) per block
#define TAG_MAGIC 0x7E57A11Bu

typedef __hip_bfloat16 bf16;
typedef unsigned long long u64;
typedef unsigned int u32;

// ---- workspace layout (float offsets) ----
// OFF_TAG must NOT alias the gin region [0, 4194304) (R9 lesson). R12 lesson:
// the harness may POISON the workspace with nonzero garbage, so readiness is
// signalled by an exact MAGIC value (same robustness class as the hpub
// protocol's exact step-tags, which survived 8 rounds) — NOT by "nonzero".
#define OFF_GIN   0
#define OFF_ALPHA 0                      // overlays gin after recurrence
#define OFF_ATT   524288
#define OFF_NRM   1048576
#define OFF_NP    1089536
#define OFF_PMP   1179648                // pair_max partials (dead gin space)
#define OFF_HS    (4*LQ*G4)              // 4194304
#define OFF_HPUB  (OFF_HS + 4*LQ*HH)     // 5242880 (u64 region, ends 7340032)
#define OFF_TAG   (OFF_HPUB + 2*4*LQ*HH) // 7340032 (u32[4][4][16], virgin space)
#define WS_NEEDED ((OFF_TAG + 1024) * 4ULL)

// agent-coherent 32-bit load (bypasses L1/L2 — always fresh across XCDs)
__device__ __forceinline__ float load_f32_agent(const float* p){
  u32 v = __hip_atomic_load((const u32*)p, __ATOMIC_RELAXED, __HIP_MEMORY_SCOPE_AGENT);
  return __uint_as_float(v);
}

__global__ __launch_bounds__(256) void k_sentinel(float* __restrict__ outp, float code)
{
  const int i = blockIdx.x*256 + threadIdx.x;
  if (i < 3072) outp[i] = code;
}

// ============ 1+2. fused gather-GEMM + LSTM recurrence ============
// Blocks 0..127: LSTM role (R4 config — proven, ~790us). Blocks 128..383:
// gather role — each computes one 128x128 gin tile (K=300) and publishes a
// MAGIC ready-tag (RELEASE, agent). LSTM blocks ACQUIRE-poll the 4 gate-tile
// tags only when crossing a 128-row m-tile (4x per 512 steps). Deadlock-free:
// gather blocks have no deps (always finish, free slots); all 128 LSTM
// blocks co-reside; worst-case dispatch order degenerates to serial
// gather-then-LSTM, never deadlock. Poison-robust: tags compare against
// TAG_MAGIC; gin bias loads are agent-coherent atomics.
__global__ __launch_bounds__(512)
__attribute__((amdgpu_waves_per_eu(1,2)))
void k_fusedgl(
    const float* __restrict__ emb, const int* __restrict__ q1_ids, const int* __restrict__ q2_ids,
    const float* __restrict__ wih0, const float* __restrict__ wih1,
    const float* __restrict__ wih2, const float* __restrict__ wih3,
    const float* __restrict__ whh0, const float* __restrict__ whh1,
    const float* __restrict__ whh2, const float* __restrict__ whh3,
    float* __restrict__ gin, float* __restrict__ hs, u64* __restrict__ hpub,
    u32* __restrict__ tags)
{
  __shared__ __align__(16) float As[16][132];
  __shared__ __align__(16) float Bs[16][132];
  __shared__ int rowid[128];
  __shared__ __align__(16) float h_lds[HH];
  __shared__ float gdot[64];
  const int tid = threadIdx.x;

  if (blockIdx.x >= 128) {
    // ---------------- gather role ----------------
    const int gi = blockIdx.x - 128;          // 0..255
    const int g2 = gi & 3, mt = (gi >> 2) & 3, nt = gi >> 4;
    const int* ids = (g2 < 2) ? q1_ids : q2_ids;
    const float* wih = (g2==0)?wih0:(g2==1)?wih1:(g2==2)?wih2:wih3;
    const int m0 = mt*128, n0 = nt*128;
    if (tid < 128) rowid[tid] = ids[m0 + tid];
    __syncthreads();
    const int tx = tid & 15, ty = tid >> 4;   // ty 0..31 (4 rows), tx (8 cols)
    float acc[4][8] = {};
    for (int k0 = 0; k0 < EE; k0 += 16) {
      for (int idx = tid; idx < 2048; idx += 512) {
        int r = idx >> 4, kk = idx & 15;
        int k = k0 + kk;
        As[kk][r] = (k < EE) ? emb[(size_t)rowid[r]*EE + k] : 0.f;
        Bs[kk][r] = (k < EE) ? wih[(size_t)(n0+r)*EE + k] : 0.f;
      }
      __syncthreads();
      #pragma unroll
      for (int kk=0;kk<16;kk++){
        float4 a  = *reinterpret_cast<const float4*>(&As[kk][ty*4]);
        float4 b0 = *reinterpret_cast<const float4*>(&Bs[kk][tx*8]);
        float4 b1 = *reinterpret_cast<const float4*>(&Bs[kk][tx*8+4]);
        #define FMA8(u, av) \
          acc[u][0]=fmaf(av,b0.x,acc[u][0]); acc[u][1]=fmaf(av,b0.y,acc[u][1]); \
          acc[u][2]=fmaf(av,b0.z,acc[u][2]); acc[u][3]=fmaf(av,b0.w,acc[u][3]); \
          acc[u][4]=fmaf(av,b1.x,acc[u][4]); acc[u][5]=fmaf(av,b1.y,acc[u][5]); \
          acc[u][6]=fmaf(av,b1.z,acc[u][6]); acc[u][7]=fmaf(av,b1.w,acc[u][7]);
        FMA8(0, a.x) FMA8(1, a.y) FMA8(2, a.z) FMA8(3, a.w)
        #undef FMA8
      }
      __syncthreads();
    }
    float* og = gin + (size_t)g2*LQ*G4;
    #pragma unroll
    for (int u=0;u<4;u++){
      float4 lo = make_float4(acc[u][0],acc[u][1],acc[u][2],acc[u][3]);
      float4 hi = make_float4(acc[u][4],acc[u][5],acc[u][6],acc[u][7]);
      *reinterpret_cast<float4*>(&og[(size_t)(m0+ty*4+u)*G4 + n0+tx*8])   = lo;
      *reinterpret_cast<float4*>(&og[(size_t)(m0+ty*4+u)*G4 + n0+tx*8+4]) = hi;
    }
    __threadfence();
    __syncthreads();   // all threads' gin stores drained before tag release
    if (tid == 0)
      __hip_atomic_store(&tags[(g2*4+mt)*16+nt], TAG_MAGIC,
                         __ATOMIC_RELEASE, __HIP_MEMORY_SCOPE_AGENT);
    return;
  }

  // ---------------- LSTM role (R4 config) ----------------
  const int g = (blockIdx.x >> 1) & 3;                       // XCD pair {2g,2g+1}
  const int b = ((blockIdx.x >> 3) << 1) | (blockIdx.x & 1); // 0..31
  const float* whh = (g==0)?whh0:(g==1)?whh1:(g==2)?whh2:whh3;
  const int row_local = tid >> 3;   // 0..63
  const int chunk = tid & 7;        // 0..7
  const int gate = row_local >> 4;
  const int jj = row_local & 15;
  const int grow = gate*HH + b*JPB + jj;
  const int rot = chunk;            // rotation in float4 units (mod 16)
  const int nt0 = b >> 3;           // this block's n-subtile within each gate

  // 16 named float4 registers: w{q} = Whh[grow][chunk*64 + ((q+rot)&15)*4 ..]
  const float4* wv4 = reinterpret_cast<const float4*>(whh + (size_t)grow*HH + chunk*64);
  float4 w0  = wv4[(0  + rot) & 15];
  float4 w1  = wv4[(1  + rot) & 15];
  float4 w2  = wv4[(2  + rot) & 15];
  float4 w3  = wv4[(3  + rot) & 15];
  float4 w4  = wv4[(4  + rot) & 15];
  float4 w5  = wv4[(5  + rot) & 15];
  float4 w6  = wv4[(6  + rot) & 15];
  float4 w7  = wv4[(7  + rot) & 15];
  float4 w8  = wv4[(8  + rot) & 15];
  float4 w9  = wv4[(9  + rot) & 15];
  float4 w10 = wv4[(10 + rot) & 15];
  float4 w11 = wv4[(11 + rot) & 15];
  float4 w12 = wv4[(12 + rot) & 15];
  float4 w13 = wv4[(13 + rot) & 15];
  float4 w14 = wv4[(14 + rot) & 15];
  float4 w15 = wv4[(15 + rot) & 15];

  const float* ginp = gin + (size_t)g*LQ*G4;
  float* hsg = hs + (size_t)g*LQ*HH;
  u64* hpg = hpub + (size_t)g*LQ*HH;
  const bool fwd = ((g & 1) == 0);

  // wait for a gin m-tile's 4 gate-subtiles (uniform across block)
  #define WAIT_TILE(mt_) { \
    if (tid < 64) { \
      const int gt_ = tid >> 4; \
      const u32* tp_ = tags + ((g*4 + (mt_))*16) + gt_*4 + nt0; \
      while (__hip_atomic_load(tp_, __ATOMIC_ACQUIRE, __HIP_MEMORY_SCOPE_AGENT) != TAG_MAGIC) {} \
    } \
    __syncthreads(); \
  }

  // software-pipelined gate-bias: wave 0 lane l owns gate (l>>4), elem (l&15)
  float pg_cur = 0.f, pg_nxt = 0.f, creg = 0.f;
  {
    const int sidx0 = fwd ? 0 : (LQ-1);
    WAIT_TILE(sidx0 >> 7);
    if (tid < 64)
      pg_cur = load_f32_agent(&ginp[(size_t)sidx0*G4 + (size_t)(tid>>4)*HH + b*JPB + (tid&15)]);
  }

  for (int s=0; s<LQ; ++s) {
    const int sidx = fwd ? s : (LQ-1-s);
    if (s == 0) {
      h_lds[tid] = 0.f;
      __syncthreads();
    } else {
      const int hidx = fwd ? (s-1) : (LQ-s);
      const u64 want = (u64)(u32)(hidx + 1);
      const u64* hp = hpg + (size_t)hidx*HH + tid;
      u64 v = __hip_atomic_load(hp, __ATOMIC_RELAXED, __HIP_MEMORY_SCOPE_AGENT);
      while ((v >> 32) != want) {
        v = __hip_atomic_load(hp, __ATOMIC_RELAXED, __HIP_MEMORY_SCOPE_AGENT);
      }
      h_lds[tid] = __uint_as_float((u32)v);
      __syncthreads();
    }
    // conflict-free rotated matvec, weights in VGPRs
    float p0=0.f, p1=0.f, p2=0.f, p3=0.f;
    {
      const float4* hld4 = reinterpret_cast<const float4*>(h_lds) + (chunk << 4);
      #define MSTEP(q, pp) { float4 hh = hld4[((q)+rot)&15]; \
        pp = fmaf(w##q.x, hh.x, pp); pp = fmaf(w##q.y, hh.y, pp); \
        pp = fmaf(w##q.z, hh.z, pp); pp = fmaf(w##q.w, hh.w, pp); }
      MSTEP(0,p0)  MSTEP(1,p1)  MSTEP(2,p2)  MSTEP(3,p3)
      MSTEP(4,p0)  MSTEP(5,p1)  MSTEP(6,p2)  MSTEP(7,p3)
      MSTEP(8,p0)  MSTEP(9,p1)  MSTEP(10,p2) MSTEP(11,p3)
      MSTEP(12,p0) MSTEP(13,p1) MSTEP(14,p2) MSTEP(15,p3)
      #undef MSTEP
    }
    // next step's gate-bias prefetch; poll tile tags only at m-tile crossings
    const int snx = (s+1 < LQ) ? (s+1) : s;
    const int sidxn = fwd ? snx : (LQ-1-snx);
    if ((sidxn >> 7) != (sidx >> 7)) WAIT_TILE(sidxn >> 7);
    if (tid < 64) {
      pg_nxt = load_f32_agent(&ginp[(size_t)sidxn*G4 + (size_t)(tid>>4)*HH + b*JPB + (tid&15)]);
    }
    float partial = (p0 + p1) + (p2 + p3);
    partial += __shfl_xor(partial, 1);
    partial += __shfl_xor(partial, 2);
    partial += __shfl_xor(partial, 4);
    if (chunk == 0) gdot[row_local] = partial;
    __syncthreads();
    // parallel gate tail: wave 0 lane l handles gate (l>>4), elem (l&15)
    if (tid < 64) {
      float x = gdot[tid] + pg_cur;
      const int gt = tid >> 4;
      float t = (gt == 2) ? 2.f*x : x;
      t = fminf(fmaxf(t, -30.f), 30.f);
      float sg = 1.f/(1.f + __expf(-t));
      float y = (gt == 2) ? 2.f*sg - 1.f : sg;     // tanh = 2*sigmoid(2x)-1
      float vf = __shfl_down(y, 16);
      float vg = __shfl_down(y, 32);
      float vo = __shfl_down(y, 48);
      if (tid < 16) {
        float c = vf*creg + y*vg;
        creg = c;
        float tc = fminf(fmaxf(2.f*c, -30.f), 30.f);
        float th = 2.f/(1.f + __expf(-tc)) - 1.f;
        float h = vo*th;
        const int j = b*JPB + tid;
        u64 pack = ((u64)(u32)(sidx + 1) << 32) | (u64)__float_as_uint(h);
        __hip_atomic_store(hpg + (size_t)sidx*HH + j, pack,
                           __ATOMIC_RELAXED, __HIP_MEMORY_SCOPE_AGENT);
        hsg[(size_t)sidx*HH + j] = h;
      }
      pg_cur = pg_nxt;
    }
  }
  #undef WAIT_TILE
}

// ============ 3. norms — wave-parallel, no barriers in k-loop ============
__global__ __launch_bounds__(256) void k_norms(
    const float* __restrict__ hs, const float* __restrict__ W3, const float* __restrict__ W4,
    float* __restrict__ nrm, float* __restrict__ np_)
{
  const int l = blockIdx.x;
  const int which = blockIdx.y;  // 0:q1p/W3 1:q2p/W3 2:q1n/W4 3:q2n/W4
  const int hsidx = (which==0)?0:(which==1)?2:(which==2)?1:3;
  const float* P = hs + (size_t)hsidx*LQ*HH + (size_t)l*HH;
  const float* Wt = (which < 2) ? W3 : W4;
  const int tid = threadIdx.x;
  const int w = tid >> 6, ln = tid & 63;
  __shared__ float p[HH];
  p[tid] = P[tid]; p[tid+256] = P[tid+256];
  __syncthreads();
  if (w == 0) {
    float v = 0.f;
    #pragma unroll
    for (int q=0;q<8;q++){ float x = p[ln+64*q]; v = fmaf(x,x,v); }
    #pragma unroll
    for (int o=32;o>0;o>>=1) v += __shfl_xor(v,o);
    if (ln==0) np_[which*LQ + l] = fmaxf(sqrtf(v), EPSF);
  }
  for (int k=w; k<WW; k+=4){
    const float* wk = Wt + (size_t)k*HH;
    float v = 0.f;
    #pragma unroll
    for (int q=0;q<8;q++){
      int e = ln + 64*q;
      float a = p[e]*wk[e];
      v = fmaf(a,a,v);
    }
    #pragma unroll
    for (int o=32;o>0;o>>=1) v += __shfl_xor(v,o);
    if (ln==0) nrm[(size_t)which*LQ*WW + (size_t)l*WW + k] = fmaxf(sqrtf(v), EPSF);
  }
}

// ============ 4. alpha = cos_pair (tiled NT GEMM, float4 LDS reads) ============
__global__ __launch_bounds__(256) void k_alpha(
    const float* __restrict__ hs, const float* __restrict__ np_, float* __restrict__ alpha)
{
  const int z = blockIdx.z;
  const float* A = hs + (size_t)(z?1:0)*LQ*HH;
  const float* B = hs + (size_t)(z?3:2)*LQ*HH;
  const float* nai = np_ + (z?2:0)*LQ;
  const float* nbj = np_ + (z?3:1)*LQ;
  float* outp = alpha + (size_t)z*LQ*LQ;
  __shared__ __align__(16) float As[16][68], Bs[16][68];
  const int tid = threadIdx.x;
  const int tx = tid & 15, ty = tid >> 4;
  const int i0 = blockIdx.y*64, j0 = blockIdx.x*64;
  float acc[4][4] = {};
  for (int k0=0;k0<HH;k0+=16){
    for (int idx=tid; idx<1024; idx+=256){
      int r = idx>>4, kk = idx&15;
      As[kk][r] = A[(size_t)(i0+r)*HH + k0+kk];
      Bs[kk][r] = B[(size_t)(j0+r)*HH + k0+kk];
    }
    __syncthreads();
    #pragma unroll
    for (int kk=0;kk<16;kk++){
      float4 a = *reinterpret_cast<const float4*>(&As[kk][ty*4]);
      float4 b = *reinterpret_cast<const float4*>(&Bs[kk][tx*4]);
      acc[0][0]=fmaf(a.x,b.x,acc[0][0]); acc[0][1]=fmaf(a.x,b.y,acc[0][1]);
      acc[0][2]=fmaf(a.x,b.z,acc[0][2]); acc[0][3]=fmaf(a.x,b.w,acc[0][3]);
      acc[1][0]=fmaf(a.y,b.x,acc[1][0]); acc[1][1]=fmaf(a.y,b.y,acc[1][1]);
      acc[1][2]=fmaf(a.y,b.z,acc[1][2]); acc[1][3]=fmaf(a.y,b.w,acc[1][3]);
      acc[2][0]=fmaf(a.z,b.x,acc[2][0]); acc[2][1]=fmaf(a.z,b.y,acc[2][1]);
      acc[2][2]=fmaf(a.z,b.z,acc[2][2]); acc[2][3]=fmaf(a.z,b.w,acc[2][3]);
      acc[3][0]=fmaf(a.w,b.x,acc[3][0]); acc[3][1]=fmaf(a.w,b.y,acc[3][1]);
      acc[3][2]=fmaf(a.w,b.z,acc[3][2]); acc[3][3]=fmaf(a.w,b.w,acc[3][3]);
    }
    __syncthreads();
  }
  #pragma unroll
  for (int u=0;u<4;u++){
    float ina = 1.f/nai[i0+ty*4+u];
    #pragma unroll
    for (int v=0;v<4;v++)
      outp[(size_t)(i0+ty*4+u)*LQ + j0+tx*4+v] = acc[u][v]*ina/nbj[j0+tx*4+v];
  }
}

// ============ 5. attention (tiled NN GEMM, rowsum fused, float4 LDS reads) ============
__global__ __launch_bounds__(256) void k_att(
    const float* __restrict__ alpha, const float* __restrict__ hs,
    float* __restrict__ att)
{
  const int z = blockIdx.z;
  const float* A = alpha + (size_t)z*LQ*LQ;
  const float* B = hs + (size_t)(z?3:2)*LQ*HH;
  float* outp = att + (size_t)z*LQ*HH;
  __shared__ __align__(16) float As[16][68], Bs[16][68];
  const int tid = threadIdx.x;
  const int tx = tid & 15, ty = tid >> 4;
  const int i0 = blockIdx.y*64, h0 = blockIdx.x*64;
  float acc[4][4] = {};
  float rsum[4] = {};
  for (int j0=0;j0<LQ;j0+=16){
    for (int idx=tid; idx<1024; idx+=256){
      int r = idx>>4, kk = idx&15;
      As[kk][r] = A[(size_t)(i0+r)*LQ + j0+kk];
    }
    for (int idx=tid; idx<1024; idx+=256){
      int jjr = idx>>6, hh = idx&63;
      Bs[jjr][hh] = B[(size_t)(j0+jjr)*HH + h0+hh];
    }
    __syncthreads();
    #pragma unroll
    for (int kk=0;kk<16;kk++){
      float4 a = *reinterpret_cast<const float4*>(&As[kk][ty*4]);
      float4 b = *reinterpret_cast<const float4*>(&Bs[kk][tx*4]);
      rsum[0]+=a.x; rsum[1]+=a.y; rsum[2]+=a.z; rsum[3]+=a.w;
      acc[0][0]=fmaf(a.x,b.x,acc[0][0]); acc[0][1]=fmaf(a.x,b.y,acc[0][1]);
      acc[0][2]=fmaf(a.x,b.z,acc[0][2]); acc[0][3]=fmaf(a.x,b.w,acc[0][3]);
      acc[1][0]=fmaf(a.y,b.x,acc[1][0]); acc[1][1]=fmaf(a.y,b.y,acc[1][1]);
      acc[1][2]=fmaf(a.y,b.z,acc[1][2]); acc[1][3]=fmaf(a.y,b.w,acc[1][3]);
      acc[2][0]=fmaf(a.z,b.x,acc[2][0]); acc[2][1]=fmaf(a.z,b.y,acc[2][1]);
      acc[2][2]=fmaf(a.z,b.z,acc[2][2]); acc[2][3]=fmaf(a.z,b.w,acc[2][3]);
      acc[3][0]=fmaf(a.w,b.x,acc[3][0]); acc[3][1]=fmaf(a.w,b.y,acc[3][1]);
      acc[3][2]=fmaf(a.w,b.z,acc[3][2]); acc[3][3]=fmaf(a.w,b.w,acc[3][3]);
    }
    __syncthreads();
  }
  #pragma unroll
  for (int u=0;u<4;u++){
    float inv = 1.f/rsum[u];
    #pragma unroll
    for (int v=0;v<4;v++)
      outp[(size_t)(i0+ty*4+u)*HH + h0+tx*4+v] = acc[u][v]*inv;
  }
}

// ============ 6. fused wcos_rows — wave-parallel, no barriers in k-loop ============
__global__ __launch_bounds__(256) void k_wcos(
    const float* __restrict__ hs, const float* __restrict__ att,
    const float* __restrict__ W1, const float* __restrict__ W2, const float* __restrict__ W5,
    float* __restrict__ outp)
{
  const int l = blockIdx.x;
  const int which = blockIdx.y;
  const int tid = threadIdx.x;
  const float* a; const float* c; const float* Wt; int m;
  switch (which) {
    case 0:  a = hs + (size_t)0*LQ*HH + (size_t)l*HH; c = hs + (size_t)2*LQ*HH + (size_t)(LQ-1)*HH; Wt = W1; m = 0; break;
    case 1:  a = hs + (size_t)1*LQ*HH + (size_t)l*HH; c = hs + (size_t)3*LQ*HH;                     Wt = W2; m = 1; break;
    case 2:  a = hs + (size_t)0*LQ*HH + (size_t)l*HH; c = att + (size_t)0*LQ*HH + (size_t)l*HH;     Wt = W5; m = 4; break;
    default: a = hs + (size_t)1*LQ*HH + (size_t)l*HH; c = att + (size_t)1*LQ*HH + (size_t)l*HH;     Wt = W5; m = 5; break;
  }
  __shared__ float av[HH], cv[HH];
  const int w = tid >> 6, ln = tid & 63;
  av[tid]=a[tid]; av[tid+256]=a[tid+256];
  cv[tid]=c[tid]; cv[tid+256]=c[tid+256];
  __syncthreads();
  for (int k=w; k<WW; k+=4){
    const float* wk = Wt + (size_t)k*HH;
    float num=0.f, na=0.f, nc=0.f;
    #pragma unroll
    for (int q=0;q<8;q++){
      int e = ln + 64*q;
      float w1 = wk[e];
      float aw = av[e]*w1;
      float cw = cv[e]*w1;
      num = fmaf(aw,cw,num);
      na  = fmaf(aw,aw,na);
      nc  = fmaf(cw,cw,nc);
    }
    #pragma unroll
    for (int o=32;o>0;o>>=1){
      num += __shfl_xor(num,o);
      na  += __shfl_xor(na,o);
      nc  += __shfl_xor(nc,o);
    }
    if (ln==0){
      float d = fmaxf(sqrtf(na),EPSF)*fmaxf(sqrtf(nc),EPSF);
      outp[((size_t)m*LQ + l)*WW + k] = num/d;
    }
  }
}

// ============ 7. pair_max v2 — weighted outer-product form (R8 proven) ============
__global__ __launch_bounds__(256) void k_pairmax(
    const float* __restrict__ hs, const float* __restrict__ W3, const float* __restrict__ W4,
    const float* __restrict__ nrm, float* __restrict__ pm_part)
{
  const int it = blockIdx.x;        // 0..7  (64-row i tile)
  const int jt = blockIdx.y;        // 0..15 (32-col j tile)
  const int z  = blockIdx.z;        // mm*2 + kh
  const int mm = z >> 1, kh = z & 1;
  const int k0 = kh*10;
  const float* A = hs + (size_t)(mm?1:0)*LQ*HH;
  const float* B = hs + (size_t)(mm?3:2)*LQ*HH;
  const float* Wt = mm ? W4 : W3;
  const float* nb = nrm + (size_t)(mm?3:1)*LQ*WW;
  const int tid = threadIdx.x;
  const int tx = tid & 31;          // j within tile
  const int ty = tid >> 5;          // i-group (8 rows each)
  const int i0 = it*64;
  const int j  = jt*32 + tx;

  __shared__ __align__(16) float As[64][128];
  __shared__ __align__(16) float Bs[32][132];
  __shared__ __align__(16) float Ws[10][128];

  float acc[8][10];
  #pragma unroll
  for (int r=0;r<8;r++)
    #pragma unroll
    for (int q=0;q<10;q++) acc[r][q]=0.f;

  for (int hc=0; hc<4; ++hc){
    const int hbase = hc*128;
    for (int idx=tid; idx<2048; idx+=256){
      int row = idx >> 5, c4 = idx & 31;
      *reinterpret_cast<float4*>(&As[row][c4*4]) =
        *reinterpret_cast<const float4*>(&A[(size_t)(i0+row)*HH + hbase + c4*4]);
    }
    for (int idx=tid; idx<1024; idx+=256){
      int row = idx >> 5, c4 = idx & 31;
      *reinterpret_cast<float4*>(&Bs[row][c4*4]) =
        *reinterpret_cast<const float4*>(&B[(size_t)(jt*32+row)*HH + hbase + c4*4]);
    }
    for (int idx=tid; idx<1280; idx+=256){
      int kk = idx >> 7, cc = idx & 127;
      float wv = Wt[(size_t)(k0+kk)*HH + hbase + cc];
      Ws[kk][cc] = wv*wv;
    }
    __syncthreads();
    #pragma unroll 2
    for (int h4=0; h4<32; ++h4){
      float4 b = *reinterpret_cast<const float4*>(&Bs[tx][h4*4]);
      float4 sa[8];
      #pragma unroll
      for (int r=0;r<8;r++){
        float4 a = *reinterpret_cast<const float4*>(&As[ty*8+r][h4*4]);
        sa[r].x = a.x*b.x; sa[r].y = a.y*b.y;
        sa[r].z = a.z*b.z; sa[r].w = a.w*b.w;
      }
      #pragma unroll
      for (int q=0;q<10;q++){
        float4 w = *reinterpret_cast<const float4*>(&Ws[q][h4*4]);
        #pragma unroll
        for (int r=0;r<8;r++){
          acc[r][q] = fmaf(sa[r].x, w.x, acc[r][q]);
          acc[r][q] = fmaf(sa[r].y, w.y, acc[r][q]);
          acc[r][q] = fmaf(sa[r].z, w.z, acc[r][q]);
          acc[r][q] = fmaf(sa[r].w, w.w, acc[r][q]);
        }
      }
    }
    __syncthreads();
  }

  // epilogue: scale by 1/nb[j][k], max over the 32 j's (lane-reduce), write partials
  float nbv[10];
  #pragma unroll
  for (int q=0;q<10;q++) nbv[q] = 1.f / nb[(size_t)j*WW + k0 + q];
  #pragma unroll
  for (int r=0;r<8;r++){
    #pragma unroll
    for (int q=0;q<10;q++){
      float v = acc[r][q] * nbv[q];
      #pragma unroll
      for (int o=1;o<32;o<<=1) v = fmaxf(v, __shfl_xor(v, o, 32));
      if (tx==0)
        pm_part[((((size_t)z*8 + it)*16 + jt)*64 + (ty*8+r))*10 + q] = v;
    }
  }
}

// ============ 8. pair_max finish: reduce 16 jt partials, divide by na ============
__global__ __launch_bounds__(256) void k_pmfin(
    const float* __restrict__ pm_part, const float* __restrict__ nrm,
    float* __restrict__ outp)
{
  const int idx = blockIdx.x*256 + threadIdx.x;   // 0..20479
  if (idx >= 2*LQ*WW) return;
  const int mm = idx / (LQ*WW);
  const int rem = idx - mm*LQ*WW;
  const int i = rem / WW, k = rem % WW;
  const int it = i >> 6, il = i & 63;
  const int kh = k / 10, kl = k % 10;
  const int z = mm*2 + kh;
  float v = -3.4e38f;
  #pragma unroll
  for (int jt=0; jt<16; ++jt)
    v = fmaxf(v, pm_part[((((size_t)z*8 + it)*16 + jt)*64 + il)*10 + kl]);
  const float* na = nrm + (size_t)(mm?2:0)*LQ*WW;
  outp[((size_t)(mm+2)*LQ + i)*WW + k] = v / na[(size_t)i*WW + k];
}

extern "C" void kernel_launch(void* const* d_in, const int* in_sizes, int n_in,
                              void* d_out, int out_size, void* d_ws, size_t ws_size,
                              hipStream_t stream)
{
  float* outp = (float*)d_out;

  float code = 0.f;
  if (n_in != 19)                    code = 101.f;
  else if (in_sizes[0]  != 512)      code = 102.f;
  else if (in_sizes[4]  != 9000000)  code = 104.f;
  else if (in_sizes[6]  != 1048576)  code = 106.f;
  else if (out_size     != 61440)    code = 108.f;
  else if (ws_size      < WS_NEEDED) code = 109.f;
  if (code != 0.f) {
    k_sentinel<<<12, 256, 0, stream>>>(outp, code);
    return;
  }

  const int* q1_ids = (const int*)d_in[0];
  const int* q2_ids = (const int*)d_in[1];
  const float* emb      = (const float*)d_in[4];
  const float* q1_wih_f = (const float*)d_in[5];
  const float* q1_whh_f = (const float*)d_in[6];
  const float* q1_wih_b = (const float*)d_in[7];
  const float* q1_whh_b = (const float*)d_in[8];
  const float* q2_wih_f = (const float*)d_in[9];
  const float* q2_whh_f = (const float*)d_in[10];
  const float* q2_wih_b = (const float*)d_in[11];
  const float* q2_whh_b = (const float*)d_in[12];
  const float* W1 = (const float*)d_in[13];
  const float* W2 = (const float*)d_in[14];
  const float* W3 = (const float*)d_in[15];
  const float* W4 = (const float*)d_in[16];
  const float* W5 = (const float*)d_in[17];
  float* ws = (float*)d_ws;

  float* gin   = ws + OFF_GIN;
  float* hsv   = ws + OFF_HS;
  u64*   hpub  = (u64*)(ws + OFF_HPUB);
  float* alpha = ws + OFF_ALPHA;
  float* att   = ws + OFF_ATT;
  float* nrm   = ws + OFF_NRM;
  float* np_   = ws + OFF_NP;
  u32*   tags  = (u32*)(ws + OFF_TAG);
  float* pmp   = ws + OFF_PMP;

  k_fusedgl<<<dim3(384), 512, 0, stream>>>(emb, q1_ids, q2_ids,
      q1_wih_f, q1_wih_b, q2_wih_f, q2_wih_b,
      q1_whh_f, q1_whh_b, q2_whh_f, q2_whh_b,
      gin, hsv, hpub, tags);
  k_norms<<<dim3(LQ,4), 256, 0, stream>>>(hsv, W3, W4, nrm, np_);
  k_alpha<<<dim3(8,8,2), 256, 0, stream>>>(hsv, np_, alpha);
  k_att<<<dim3(8,8,2), 256, 0, stream>>>(alpha, hsv, att);
  k_wcos<<<dim3(LQ,4), 256, 0, stream>>>(hsv, att, W1, W2, W5, outp);
  k_pairmax<<<dim3(8,16,4), 256, 0, stream>>>(hsv, W3, W4, nrm, pmp);
  k_pmfin<<<dim3(80), 256, 0, stream>>>(pmp, nrm, outp);
}

// Round 13
// 1373.447 us; speedup vs baseline: 1.1034x; 1.1034x over previous
//
#include <hip/hip_runtime.h>
#include <hip/hip_bf16.h>
#include <math.h>

#define LQ 512
#define HH 512
#define EE 300
#define WW 20
#define G4 2048
#define EPSF 1e-8f
#define RB 32   // blocks per LSTM in recurrence
#define JPB 16  // j (h-elements) per block
#define TAG_MAGIC 0x7E57A11Bu

typedef __hip_bfloat16 bf16;
typedef unsigned long long u64;
typedef unsigned int u32;

// ---- workspace layout (float offsets) ----
// OFF_TAG must NOT alias gin (R9 lesson); readiness = exact MAGIC (R12 lesson,
// poison-robust). R13: block-role ORDER fixed — urgency-0 gather tiles (the
// m-tile each LSTM reads FIRST: mt=0 fwd, mt=3 bwd) occupy blockIdx 0..63 so
// they are co-resident with the LSTM blocks from dispatch wave one; R12 had
// gates 2,3 tiles in blocks 256+, serializing LSTM start behind ~2 gather
// passes (1155us fused).
#define OFF_GIN   0
#define OFF_ALPHA 0                      // overlays gin after recurrence
#define OFF_ATT   524288
#define OFF_NRM   1048576
#define OFF_NP    1089536
#define OFF_PMP   1179648                // pair_max partials (dead gin space)
#define OFF_HS    (4*LQ*G4)              // 4194304
#define OFF_HPUB  (OFF_HS + 4*LQ*HH)     // 5242880 (u64 region, ends 7340032)
#define OFF_TAG   (OFF_HPUB + 2*4*LQ*HH) // 7340032 (u32[4][4][16], virgin space)
#define WS_NEEDED ((OFF_TAG + 1024) * 4ULL)

// agent-coherent 32-bit load (bypasses L1/L2 — always fresh across XCDs)
__device__ __forceinline__ float load_f32_agent(const float* p){
  u32 v = __hip_atomic_load((const u32*)p, __ATOMIC_RELAXED, __HIP_MEMORY_SCOPE_AGENT);
  return __uint_as_float(v);
}

__global__ __launch_bounds__(256) void k_sentinel(float* __restrict__ outp, float code)
{
  const int i = blockIdx.x*256 + threadIdx.x;
  if (i < 3072) outp[i] = code;
}

// ============ 1+2. fused gather-GEMM + LSTM recurrence ============
// Grid 384: blocks 0..63 = gather urgency-0 (mt each LSTM needs first);
// blocks 64..191 = LSTM (R4 config); blocks 192..383 = gather urgency 1..3.
// Gather block gi (0..255): u=gi>>6, g2=(gi>>4)&3, nt=gi&15,
// mt = fwd(g2) ? u : 3-u. Publishes MAGIC tag (RELEASE). LSTM acquires-polls
// the 4 gate-subtile tags at 128-row m-tile crossings. Deadlock-free: gather
// has no deps; 128 LSTM blocks <= free slots; worst-case order = serial.
__global__ __launch_bounds__(512)
__attribute__((amdgpu_waves_per_eu(1,2)))
void k_fusedgl(
    const float* __restrict__ emb, const int* __restrict__ q1_ids, const int* __restrict__ q2_ids,
    const float* __restrict__ wih0, const float* __restrict__ wih1,
    const float* __restrict__ wih2, const float* __restrict__ wih3,
    const float* __restrict__ whh0, const float* __restrict__ whh1,
    const float* __restrict__ whh2, const float* __restrict__ whh3,
    float* __restrict__ gin, float* __restrict__ hs, u64* __restrict__ hpub,
    u32* __restrict__ tags)
{
  __shared__ __align__(16) float As[16][132];
  __shared__ __align__(16) float Bs[16][132];
  __shared__ int rowid[128];
  __shared__ __align__(16) float h_lds[HH];
  __shared__ float gdot[64];
  const int tid = threadIdx.x;
  const int bid = blockIdx.x;
  const bool is_lstm = (bid >= 64 && bid < 192);

  if (!is_lstm) {
    // ---------------- gather role ----------------
    const int gi = (bid < 64) ? bid : (bid - 128);   // 0..63 | 64..255
    const int u  = gi >> 6;                          // urgency 0..3
    const int g2 = (gi >> 4) & 3;
    const int nt = gi & 15;
    const int mt = ((g2 & 1) == 0) ? u : 3 - u;      // fwd consumes mt 0 first; bwd mt 3
    const int* ids = (g2 < 2) ? q1_ids : q2_ids;
    const float* wih = (g2==0)?wih0:(g2==1)?wih1:(g2==2)?wih2:wih3;
    const int m0 = mt*128, n0 = nt*128;
    if (tid < 128) rowid[tid] = ids[m0 + tid];
    __syncthreads();
    const int tx = tid & 15, ty = tid >> 4;   // ty 0..31 (4 rows), tx (8 cols)
    float acc[4][8] = {};
    for (int k0 = 0; k0 < EE; k0 += 16) {
      for (int idx = tid; idx < 2048; idx += 512) {
        int r = idx >> 4, kk = idx & 15;
        int k = k0 + kk;
        As[kk][r] = (k < EE) ? emb[(size_t)rowid[r]*EE + k] : 0.f;
        Bs[kk][r] = (k < EE) ? wih[(size_t)(n0+r)*EE + k] : 0.f;
      }
      __syncthreads();
      #pragma unroll
      for (int kk=0;kk<16;kk++){
        float4 a  = *reinterpret_cast<const float4*>(&As[kk][ty*4]);
        float4 b0 = *reinterpret_cast<const float4*>(&Bs[kk][tx*8]);
        float4 b1 = *reinterpret_cast<const float4*>(&Bs[kk][tx*8+4]);
        #define FMA8(u_, av) \
          acc[u_][0]=fmaf(av,b0.x,acc[u_][0]); acc[u_][1]=fmaf(av,b0.y,acc[u_][1]); \
          acc[u_][2]=fmaf(av,b0.z,acc[u_][2]); acc[u_][3]=fmaf(av,b0.w,acc[u_][3]); \
          acc[u_][4]=fmaf(av,b1.x,acc[u_][4]); acc[u_][5]=fmaf(av,b1.y,acc[u_][5]); \
          acc[u_][6]=fmaf(av,b1.z,acc[u_][6]); acc[u_][7]=fmaf(av,b1.w,acc[u_][7]);
        FMA8(0, a.x) FMA8(1, a.y) FMA8(2, a.z) FMA8(3, a.w)
        #undef FMA8
      }
      __syncthreads();
    }
    float* og = gin + (size_t)g2*LQ*G4;
    #pragma unroll
    for (int u_=0;u_<4;u_++){
      float4 lo = make_float4(acc[u_][0],acc[u_][1],acc[u_][2],acc[u_][3]);
      float4 hi = make_float4(acc[u_][4],acc[u_][5],acc[u_][6],acc[u_][7]);
      *reinterpret_cast<float4*>(&og[(size_t)(m0+ty*4+u_)*G4 + n0+tx*8])   = lo;
      *reinterpret_cast<float4*>(&og[(size_t)(m0+ty*4+u_)*G4 + n0+tx*8+4]) = hi;
    }
    __threadfence();
    __syncthreads();   // all threads' gin stores drained before tag release
    if (tid == 0)
      __hip_atomic_store(&tags[(g2*4+mt)*16+nt], TAG_MAGIC,
                         __ATOMIC_RELEASE, __HIP_MEMORY_SCOPE_AGENT);
    return;
  }

  // ---------------- LSTM role (R4 config) ----------------
  const int lid = bid - 64;                          // 0..127; lid%8 == bid%8 - preserves XCD map
  const int g = (lid >> 1) & 3;                      // XCD pair {2g,2g+1}
  const int b = ((lid >> 3) << 1) | (lid & 1);       // 0..31
  const float* whh = (g==0)?whh0:(g==1)?whh1:(g==2)?whh2:whh3;
  const int row_local = tid >> 3;   // 0..63
  const int chunk = tid & 7;        // 0..7
  const int gate = row_local >> 4;
  const int jj = row_local & 15;
  const int grow = gate*HH + b*JPB + jj;
  const int rot = chunk;            // rotation in float4 units (mod 16)
  const int nt0 = b >> 3;           // this block's n-subtile within each gate

  // 16 named float4 registers: w{q} = Whh[grow][chunk*64 + ((q+rot)&15)*4 ..]
  const float4* wv4 = reinterpret_cast<const float4*>(whh + (size_t)grow*HH + chunk*64);
  float4 w0  = wv4[(0  + rot) & 15];
  float4 w1  = wv4[(1  + rot) & 15];
  float4 w2  = wv4[(2  + rot) & 15];
  float4 w3  = wv4[(3  + rot) & 15];
  float4 w4  = wv4[(4  + rot) & 15];
  float4 w5  = wv4[(5  + rot) & 15];
  float4 w6  = wv4[(6  + rot) & 15];
  float4 w7  = wv4[(7  + rot) & 15];
  float4 w8  = wv4[(8  + rot) & 15];
  float4 w9  = wv4[(9  + rot) & 15];
  float4 w10 = wv4[(10 + rot) & 15];
  float4 w11 = wv4[(11 + rot) & 15];
  float4 w12 = wv4[(12 + rot) & 15];
  float4 w13 = wv4[(13 + rot) & 15];
  float4 w14 = wv4[(14 + rot) & 15];
  float4 w15 = wv4[(15 + rot) & 15];

  const float* ginp = gin + (size_t)g*LQ*G4;
  float* hsg = hs + (size_t)g*LQ*HH;
  u64* hpg = hpub + (size_t)g*LQ*HH;
  const bool fwd = ((g & 1) == 0);

  // wait for a gin m-tile's 4 gate-subtiles (uniform across block)
  #define WAIT_TILE(mt_) { \
    if (tid < 64) { \
      const int gt_ = tid >> 4; \
      const u32* tp_ = tags + ((g*4 + (mt_))*16) + gt_*4 + nt0; \
      while (__hip_atomic_load(tp_, __ATOMIC_ACQUIRE, __HIP_MEMORY_SCOPE_AGENT) != TAG_MAGIC) {} \
    } \
    __syncthreads(); \
  }

  // software-pipelined gate-bias: wave 0 lane l owns gate (l>>4), elem (l&15)
  float pg_cur = 0.f, pg_nxt = 0.f, creg = 0.f;
  {
    const int sidx0 = fwd ? 0 : (LQ-1);
    WAIT_TILE(sidx0 >> 7);
    if (tid < 64)
      pg_cur = load_f32_agent(&ginp[(size_t)sidx0*G4 + (size_t)(tid>>4)*HH + b*JPB + (tid&15)]);
  }

  for (int s=0; s<LQ; ++s) {
    const int sidx = fwd ? s : (LQ-1-s);
    if (s == 0) {
      h_lds[tid] = 0.f;
      __syncthreads();
    } else {
      const int hidx = fwd ? (s-1) : (LQ-s);
      const u64 want = (u64)(u32)(hidx + 1);
      const u64* hp = hpg + (size_t)hidx*HH + tid;
      u64 v = __hip_atomic_load(hp, __ATOMIC_RELAXED, __HIP_MEMORY_SCOPE_AGENT);
      while ((v >> 32) != want) {
        v = __hip_atomic_load(hp, __ATOMIC_RELAXED, __HIP_MEMORY_SCOPE_AGENT);
      }
      h_lds[tid] = __uint_as_float((u32)v);
      __syncthreads();
    }
    // conflict-free rotated matvec, weights in VGPRs
    float p0=0.f, p1=0.f, p2=0.f, p3=0.f;
    {
      const float4* hld4 = reinterpret_cast<const float4*>(h_lds) + (chunk << 4);
      #define MSTEP(q, pp) { float4 hh = hld4[((q)+rot)&15]; \
        pp = fmaf(w##q.x, hh.x, pp); pp = fmaf(w##q.y, hh.y, pp); \
        pp = fmaf(w##q.z, hh.z, pp); pp = fmaf(w##q.w, hh.w, pp); }
      MSTEP(0,p0)  MSTEP(1,p1)  MSTEP(2,p2)  MSTEP(3,p3)
      MSTEP(4,p0)  MSTEP(5,p1)  MSTEP(6,p2)  MSTEP(7,p3)
      MSTEP(8,p0)  MSTEP(9,p1)  MSTEP(10,p2) MSTEP(11,p3)
      MSTEP(12,p0) MSTEP(13,p1) MSTEP(14,p2) MSTEP(15,p3)
      #undef MSTEP
    }
    // next step's gate-bias prefetch; poll tile tags only at m-tile crossings
    const int snx = (s+1 < LQ) ? (s+1) : s;
    const int sidxn = fwd ? snx : (LQ-1-snx);
    if ((sidxn >> 7) != (sidx >> 7)) WAIT_TILE(sidxn >> 7);
    if (tid < 64) {
      pg_nxt = load_f32_agent(&ginp[(size_t)sidxn*G4 + (size_t)(tid>>4)*HH + b*JPB + (tid&15)]);
    }
    float partial = (p0 + p1) + (p2 + p3);
    partial += __shfl_xor(partial, 1);
    partial += __shfl_xor(partial, 2);
    partial += __shfl_xor(partial, 4);
    if (chunk == 0) gdot[row_local] = partial;
    __syncthreads();
    // parallel gate tail: wave 0 lane l handles gate (l>>4), elem (l&15)
    if (tid < 64) {
      float x = gdot[tid] + pg_cur;
      const int gt = tid >> 4;
      float t = (gt == 2) ? 2.f*x : x;
      t = fminf(fmaxf(t, -30.f), 30.f);
      float sg = 1.f/(1.f + __expf(-t));
      float y = (gt == 2) ? 2.f*sg - 1.f : sg;     // tanh = 2*sigmoid(2x)-1
      float vf = __shfl_down(y, 16);
      float vg = __shfl_down(y, 32);
      float vo = __shfl_down(y, 48);
      if (tid < 16) {
        float c = vf*creg + y*vg;
        creg = c;
        float tc = fminf(fmaxf(2.f*c, -30.f), 30.f);
        float th = 2.f/(1.f + __expf(-tc)) - 1.f;
        float h = vo*th;
        const int j = b*JPB + tid;
        u64 pack = ((u64)(u32)(sidx + 1) << 32) | (u64)__float_as_uint(h);
        __hip_atomic_store(hpg + (size_t)sidx*HH + j, pack,
                           __ATOMIC_RELAXED, __HIP_MEMORY_SCOPE_AGENT);
        hsg[(size_t)sidx*HH + j] = h;
      }
      pg_cur = pg_nxt;
    }
  }
  #undef WAIT_TILE
}

// ============ 3. norms — wave-parallel, no barriers in k-loop ============
__global__ __launch_bounds__(256) void k_norms(
    const float* __restrict__ hs, const float* __restrict__ W3, const float* __restrict__ W4,
    float* __restrict__ nrm, float* __restrict__ np_)
{
  const int l = blockIdx.x;
  const int which = blockIdx.y;  // 0:q1p/W3 1:q2p/W3 2:q1n/W4 3:q2n/W4
  const int hsidx = (which==0)?0:(which==1)?2:(which==2)?1:3;
  const float* P = hs + (size_t)hsidx*LQ*HH + (size_t)l*HH;
  const float* Wt = (which < 2) ? W3 : W4;
  const int tid = threadIdx.x;
  const int w = tid >> 6, ln = tid & 63;
  __shared__ float p[HH];
  p[tid] = P[tid]; p[tid+256] = P[tid+256];
  __syncthreads();
  if (w == 0) {
    float v = 0.f;
    #pragma unroll
    for (int q=0;q<8;q++){ float x = p[ln+64*q]; v = fmaf(x,x,v); }
    #pragma unroll
    for (int o=32;o>0;o>>=1) v += __shfl_xor(v,o);
    if (ln==0) np_[which*LQ + l] = fmaxf(sqrtf(v), EPSF);
  }
  for (int k=w; k<WW; k+=4){
    const float* wk = Wt + (size_t)k*HH;
    float v = 0.f;
    #pragma unroll
    for (int q=0;q<8;q++){
      int e = ln + 64*q;
      float a = p[e]*wk[e];
      v = fmaf(a,a,v);
    }
    #pragma unroll
    for (int o=32;o>0;o>>=1) v += __shfl_xor(v,o);
    if (ln==0) nrm[(size_t)which*LQ*WW + (size_t)l*WW + k] = fmaxf(sqrtf(v), EPSF);
  }
}

// ============ 4. alpha = cos_pair (tiled NT GEMM, float4 LDS reads) ============
__global__ __launch_bounds__(256) void k_alpha(
    const float* __restrict__ hs, const float* __restrict__ np_, float* __restrict__ alpha)
{
  const int z = blockIdx.z;
  const float* A = hs + (size_t)(z?1:0)*LQ*HH;
  const float* B = hs + (size_t)(z?3:2)*LQ*HH;
  const float* nai = np_ + (z?2:0)*LQ;
  const float* nbj = np_ + (z?3:1)*LQ;
  float* outp = alpha + (size_t)z*LQ*LQ;
  __shared__ __align__(16) float As[16][68], Bs[16][68];
  const int tid = threadIdx.x;
  const int tx = tid & 15, ty = tid >> 4;
  const int i0 = blockIdx.y*64, j0 = blockIdx.x*64;
  float acc[4][4] = {};
  for (int k0=0;k0<HH;k0+=16){
    for (int idx=tid; idx<1024; idx+=256){
      int r = idx>>4, kk = idx&15;
      As[kk][r] = A[(size_t)(i0+r)*HH + k0+kk];
      Bs[kk][r] = B[(size_t)(j0+r)*HH + k0+kk];
    }
    __syncthreads();
    #pragma unroll
    for (int kk=0;kk<16;kk++){
      float4 a = *reinterpret_cast<const float4*>(&As[kk][ty*4]);
      float4 b = *reinterpret_cast<const float4*>(&Bs[kk][tx*4]);
      acc[0][0]=fmaf(a.x,b.x,acc[0][0]); acc[0][1]=fmaf(a.x,b.y,acc[0][1]);
      acc[0][2]=fmaf(a.x,b.z,acc[0][2]); acc[0][3]=fmaf(a.x,b.w,acc[0][3]);
      acc[1][0]=fmaf(a.y,b.x,acc[1][0]); acc[1][1]=fmaf(a.y,b.y,acc[1][1]);
      acc[1][2]=fmaf(a.y,b.z,acc[1][2]); acc[1][3]=fmaf(a.y,b.w,acc[1][3]);
      acc[2][0]=fmaf(a.z,b.x,acc[2][0]); acc[2][1]=fmaf(a.z,b.y,acc[2][1]);
      acc[2][2]=fmaf(a.z,b.z,acc[2][2]); acc[2][3]=fmaf(a.z,b.w,acc[2][3]);
      acc[3][0]=fmaf(a.w,b.x,acc[3][0]); acc[3][1]=fmaf(a.w,b.y,acc[3][1]);
      acc[3][2]=fmaf(a.w,b.z,acc[3][2]); acc[3][3]=fmaf(a.w,b.w,acc[3][3]);
    }
    __syncthreads();
  }
  #pragma unroll
  for (int u=0;u<4;u++){
    float ina = 1.f/nai[i0+ty*4+u];
    #pragma unroll
    for (int v=0;v<4;v++)
      outp[(size_t)(i0+ty*4+u)*LQ + j0+tx*4+v] = acc[u][v]*ina/nbj[j0+tx*4+v];
  }
}

// ============ 5. attention (tiled NN GEMM, rowsum fused, float4 LDS reads) ============
__global__ __launch_bounds__(256) void k_att(
    const float* __restrict__ alpha, const float* __restrict__ hs,
    float* __restrict__ att)
{
  const int z = blockIdx.z;
  const float* A = alpha + (size_t)z*LQ*LQ;
  const float* B = hs + (size_t)(z?3:2)*LQ*HH;
  float* outp = att + (size_t)z*LQ*HH;
  __shared__ __align__(16) float As[16][68], Bs[16][68];
  const int tid = threadIdx.x;
  const int tx = tid & 15, ty = tid >> 4;
  const int i0 = blockIdx.y*64, h0 = blockIdx.x*64;
  float acc[4][4] = {};
  float rsum[4] = {};
  for (int j0=0;j0<LQ;j0+=16){
    for (int idx=tid; idx<1024; idx+=256){
      int r = idx>>4, kk = idx&15;
      As[kk][r] = A[(size_t)(i0+r)*LQ + j0+kk];
    }
    for (int idx=tid; idx<1024; idx+=256){
      int jjr = idx>>6, hh = idx&63;
      Bs[jjr][hh] = B[(size_t)(j0+jjr)*HH + h0+hh];
    }
    __syncthreads();
    #pragma unroll
    for (int kk=0;kk<16;kk++){
      float4 a = *reinterpret_cast<const float4*>(&As[kk][ty*4]);
      float4 b = *reinterpret_cast<const float4*>(&Bs[kk][tx*4]);
      rsum[0]+=a.x; rsum[1]+=a.y; rsum[2]+=a.z; rsum[3]+=a.w;
      acc[0][0]=fmaf(a.x,b.x,acc[0][0]); acc[0][1]=fmaf(a.x,b.y,acc[0][1]);
      acc[0][2]=fmaf(a.x,b.z,acc[0][2]); acc[0][3]=fmaf(a.x,b.w,acc[0][3]);
      acc[1][0]=fmaf(a.y,b.x,acc[1][0]); acc[1][1]=fmaf(a.y,b.y,acc[1][1]);
      acc[1][2]=fmaf(a.y,b.z,acc[1][2]); acc[1][3]=fmaf(a.y,b.w,acc[1][3]);
      acc[2][0]=fmaf(a.z,b.x,acc[2][0]); acc[2][1]=fmaf(a.z,b.y,acc[2][1]);
      acc[2][2]=fmaf(a.z,b.z,acc[2][2]); acc[2][3]=fmaf(a.z,b.w,acc[2][3]);
      acc[3][0]=fmaf(a.w,b.x,acc[3][0]); acc[3][1]=fmaf(a.w,b.y,acc[3][1]);
      acc[3][2]=fmaf(a.w,b.z,acc[3][2]); acc[3][3]=fmaf(a.w,b.w,acc[3][3]);
    }
    __syncthreads();
  }
  #pragma unroll
  for (int u=0;u<4;u++){
    float inv = 1.f/rsum[u];
    #pragma unroll
    for (int v=0;v<4;v++)
      outp[(size_t)(i0+ty*4+u)*HH + h0+tx*4+v] = acc[u][v]*inv;
  }
}

// ============ 6. fused wcos_rows — wave-parallel, no barriers in k-loop ============
__global__ __launch_bounds__(256) void k_wcos(
    const float* __restrict__ hs, const float* __restrict__ att,
    const float* __restrict__ W1, const float* __restrict__ W2, const float* __restrict__ W5,
    float* __restrict__ outp)
{
  const int l = blockIdx.x;
  const int which = blockIdx.y;
  const int tid = threadIdx.x;
  const float* a; const float* c; const float* Wt; int m;
  switch (which) {
    case 0:  a = hs + (size_t)0*LQ*HH + (size_t)l*HH; c = hs + (size_t)2*LQ*HH + (size_t)(LQ-1)*HH; Wt = W1; m = 0; break;
    case 1:  a = hs + (size_t)1*LQ*HH + (size_t)l*HH; c = hs + (size_t)3*LQ*HH;                     Wt = W2; m = 1; break;
    case 2:  a = hs + (size_t)0*LQ*HH + (size_t)l*HH; c = att + (size_t)0*LQ*HH + (size_t)l*HH;     Wt = W5; m = 4; break;
    default: a = hs + (size_t)1*LQ*HH + (size_t)l*HH; c = att + (size_t)1*LQ*HH + (size_t)l*HH;     Wt = W5; m = 5; break;
  }
  __shared__ float av[HH], cv[HH];
  const int w = tid >> 6, ln = tid & 63;
  av[tid]=a[tid]; av[tid+256]=a[tid+256];
  cv[tid]=c[tid]; cv[tid+256]=c[tid+256];
  __syncthreads();
  for (int k=w; k<WW; k+=4){
    const float* wk = Wt + (size_t)k*HH;
    float num=0.f, na=0.f, nc=0.f;
    #pragma unroll
    for (int q=0;q<8;q++){
      int e = ln + 64*q;
      float w1 = wk[e];
      float aw = av[e]*w1;
      float cw = cv[e]*w1;
      num = fmaf(aw,cw,num);
      na  = fmaf(aw,aw,na);
      nc  = fmaf(cw,cw,nc);
    }
    #pragma unroll
    for (int o=32;o>0;o>>=1){
      num += __shfl_xor(num,o);
      na  += __shfl_xor(na,o);
      nc  += __shfl_xor(nc,o);
    }
    if (ln==0){
      float d = fmaxf(sqrtf(na),EPSF)*fmaxf(sqrtf(nc),EPSF);
      outp[((size_t)m*LQ + l)*WW + k] = num/d;
    }
  }
}

// ============ 7. pair_max v2 — weighted outer-product form (R8 proven) ============
__global__ __launch_bounds__(256) void k_pairmax(
    const float* __restrict__ hs, const float* __restrict__ W3, const float* __restrict__ W4,
    const float* __restrict__ nrm, float* __restrict__ pm_part)
{
  const int it = blockIdx.x;        // 0..7  (64-row i tile)
  const int jt = blockIdx.y;        // 0..15 (32-col j tile)
  const int z  = blockIdx.z;        // mm*2 + kh
  const int mm = z >> 1, kh = z & 1;
  const int k0 = kh*10;
  const float* A = hs + (size_t)(mm?1:0)*LQ*HH;
  const float* B = hs + (size_t)(mm?3:2)*LQ*HH;
  const float* Wt = mm ? W4 : W3;
  const float* nb = nrm + (size_t)(mm?3:1)*LQ*WW;
  const int tid = threadIdx.x;
  const int tx = tid & 31;          // j within tile
  const int ty = tid >> 5;          // i-group (8 rows each)
  const int i0 = it*64;
  const int j  = jt*32 + tx;

  __shared__ __align__(16) float As[64][128];
  __shared__ __align__(16) float Bs[32][132];
  __shared__ __align__(16) float Ws[10][128];

  float acc[8][10];
  #pragma unroll
  for (int r=0;r<8;r++)
    #pragma unroll
    for (int q=0;q<10;q++) acc[r][q]=0.f;

  for (int hc=0; hc<4; ++hc){
    const int hbase = hc*128;
    for (int idx=tid; idx<2048; idx+=256){
      int row = idx >> 5, c4 = idx & 31;
      *reinterpret_cast<float4*>(&As[row][c4*4]) =
        *reinterpret_cast<const float4*>(&A[(size_t)(i0+row)*HH + hbase + c4*4]);
    }
    for (int idx=tid; idx<1024; idx+=256){
      int row = idx >> 5, c4 = idx & 31;
      *reinterpret_cast<float4*>(&Bs[row][c4*4]) =
        *reinterpret_cast<const float4*>(&B[(size_t)(jt*32+row)*HH + hbase + c4*4]);
    }
    for (int idx=tid; idx<1280; idx+=256){
      int kk = idx >> 7, cc = idx & 127;
      float wv = Wt[(size_t)(k0+kk)*HH + hbase + cc];
      Ws[kk][cc] = wv*wv;
    }
    __syncthreads();
    #pragma unroll 2
    for (int h4=0; h4<32; ++h4){
      float4 b = *reinterpret_cast<const float4*>(&Bs[tx][h4*4]);
      float4 sa[8];
      #pragma unroll
      for (int r=0;r<8;r++){
        float4 a = *reinterpret_cast<const float4*>(&As[ty*8+r][h4*4]);
        sa[r].x = a.x*b.x; sa[r].y = a.y*b.y;
        sa[r].z = a.z*b.z; sa[r].w = a.w*b.w;
      }
      #pragma unroll
      for (int q=0;q<10;q++){
        float4 w = *reinterpret_cast<const float4*>(&Ws[q][h4*4]);
        #pragma unroll
        for (int r=0;r<8;r++){
          acc[r][q] = fmaf(sa[r].x, w.x, acc[r][q]);
          acc[r][q] = fmaf(sa[r].y, w.y, acc[r][q]);
          acc[r][q] = fmaf(sa[r].z, w.z, acc[r][q]);
          acc[r][q] = fmaf(sa[r].w, w.w, acc[r][q]);
        }
      }
    }
    __syncthreads();
  }

  // epilogue: scale by 1/nb[j][k], max over the 32 j's (lane-reduce), write partials
  float nbv[10];
  #pragma unroll
  for (int q=0;q<10;q++) nbv[q] = 1.f / nb[(size_t)j*WW + k0 + q];
  #pragma unroll
  for (int r=0;r<8;r++){
    #pragma unroll
    for (int q=0;q<10;q++){
      float v = acc[r][q] * nbv[q];
      #pragma unroll
      for (int o=1;o<32;o<<=1) v = fmaxf(v, __shfl_xor(v, o, 32));
      if (tx==0)
        pm_part[((((size_t)z*8 + it)*16 + jt)*64 + (ty*8+r))*10 + q] = v;
    }
  }
}

// ============ 8. pair_max finish: reduce 16 jt partials, divide by na ============
__global__ __launch_bounds__(256) void k_pmfin(
    const float* __restrict__ pm_part, const float* __restrict__ nrm,
    float* __restrict__ outp)
{
  const int idx = blockIdx.x*256 + threadIdx.x;   // 0..20479
  if (idx >= 2*LQ*WW) return;
  const int mm = idx / (LQ*WW);
  const int rem = idx - mm*LQ*WW;
  const int i = rem / WW, k = rem % WW;
  const int it = i >> 6, il = i & 63;
  const int kh = k / 10, kl = k % 10;
  const int z = mm*2 + kh;
  float v = -3.4e38f;
  #pragma unroll
  for (int jt=0; jt<16; ++jt)
    v = fmaxf(v, pm_part[((((size_t)z*8 + it)*16 + jt)*64 + il)*10 + kl]);
  const float* na = nrm + (size_t)(mm?2:0)*LQ*WW;
  outp[((size_t)(mm+2)*LQ + i)*WW + k] = v / na[(size_t)i*WW + k];
}

extern "C" void kernel_launch(void* const* d_in, const int* in_sizes, int n_in,
                              void* d_out, int out_size, void* d_ws, size_t ws_size,
                              hipStream_t stream)
{
  float* outp = (float*)d_out;

  float code = 0.f;
  if (n_in != 19)                    code = 101.f;
  else if (in_sizes[0]  != 512)      code = 102.f;
  else if (in_sizes[4]  != 9000000)  code = 104.f;
  else if (in_sizes[6]  != 1048576)  code = 106.f;
  else if (out_size     != 61440)    code = 108.f;
  else if (ws_size      < WS_NEEDED) code = 109.f;
  if (code != 0.f) {
    k_sentinel<<<12, 256, 0, stream>>>(outp, code);
    return;
  }

  const int* q1_ids = (const int*)d_in[0];
  const int* q2_ids = (const int*)d_in[1];
  const float* emb      = (const float*)d_in[4];
  const float* q1_wih_f = (const float*)d_in[5];
  const float* q1_whh_f = (const float*)d_in[6];
  const float* q1_wih_b = (const float*)d_in[7];
  const float* q1_whh_b = (const float*)d_in[8];
  const float* q2_wih_f = (const float*)d_in[9];
  const float* q2_whh_f = (const float*)d_in[10];
  const float* q2_wih_b = (const float*)d_in[11];
  const float* q2_whh_b = (const float*)d_in[12];
  const float* W1 = (const float*)d_in[13];
  const float* W2 = (const float*)d_in[14];
  const float* W3 = (const float*)d_in[15];
  const float* W4 = (const float*)d_in[16];
  const float* W5 = (const float*)d_in[17];
  float* ws = (float*)d_ws;

  float* gin   = ws + OFF_GIN;
  float* hsv   = ws + OFF_HS;
  u64*   hpub  = (u64*)(ws + OFF_HPUB);
  float* alpha = ws + OFF_ALPHA;
  float* att   = ws + OFF_ATT;
  float* nrm   = ws + OFF_NRM;
  float* np_   = ws + OFF_NP;
  u32*   tags  = (u32*)(ws + OFF_TAG);
  float* pmp   = ws + OFF_PMP;

  k_fusedgl<<<dim3(384), 512, 0, stream>>>(emb, q1_ids, q2_ids,
      q1_wih_f, q1_wih_b, q2_wih_f, q2_wih_b,
      q1_whh_f, q1_whh_b, q2_whh_f, q2_whh_b,
      gin, hsv, hpub, tags);
  k_norms<<<dim3(LQ,4), 256, 0, stream>>>(hsv, W3, W4, nrm, np_);
  k_alpha<<<dim3(8,8,2), 256, 0, stream>>>(hsv, np_, alpha);
  k_att<<<dim3(8,8,2), 256, 0, stream>>>(alpha, hsv, att);
  k_wcos<<<dim3(LQ,4), 256, 0, stream>>>(hsv, att, W1, W2, W5, outp);
  k_pairmax<<<dim3(8,16,4), 256, 0, stream>>>(hsv, W3, W4, nrm, pmp);
  k_pmfin<<<dim3(80), 256, 0, stream>>>(pmp, nrm, outp);
}

// Round 14
// 1207.217 us; speedup vs baseline: 1.2553x; 1.1377x over previous
//
#include <hip/hip_runtime.h>
#include <hip/hip_bf16.h>
#include <math.h>

#define LQ 512
#define HH 512
#define EE 300
#define WW 20
#define G4 2048
#define EPSF 1e-8f
#define RB 32   // blocks per LSTM in recurrence
#define JPB 16  // j (h-elements) per block

typedef __hip_bfloat16 bf16;
typedef unsigned long long u64;
typedef unsigned int u32;

// ---- workspace layout (float offsets) ----
#define OFF_GIN   0
#define OFF_ALPHA 0                      // overlays gin after k_lstm
#define OFF_ATT   524288
#define OFF_NRM   1048576
#define OFF_NP    1089536
#define OFF_PMP   1179648                // pair_max partials (dead gin space)
#define OFF_HS    (4*LQ*G4)              // 4194304
#define OFF_HPUB  (OFF_HS + 4*LQ*HH)     // 5242880 (u64 region)
#define WS_NEEDED ((OFF_HPUB + 2*4*LQ*HH) * 4ULL)

__global__ __launch_bounds__(256) void k_sentinel(float* __restrict__ outp, float code)
{
  const int i = blockIdx.x*256 + threadIdx.x;
  if (i < 3072) outp[i] = code;
}

// ============ 1. embedding gather + Wih GEMM (float4 LDS reads) ============
__global__ __launch_bounds__(256) void k_gather_gemm(
    const float* __restrict__ emb, const int* __restrict__ q1_ids, const int* __restrict__ q2_ids,
    const float* __restrict__ wih0, const float* __restrict__ wih1,
    const float* __restrict__ wih2, const float* __restrict__ wih3,
    float* __restrict__ gin)
{
  const int g = blockIdx.z;
  const int* ids = (g < 2) ? q1_ids : q2_ids;
  const float* wih = (g==0)?wih0:(g==1)?wih1:(g==2)?wih2:wih3;
  __shared__ __align__(16) float As[16][68];
  __shared__ __align__(16) float Bs[16][68];
  __shared__ int rowid[64];
  const int tid = threadIdx.x;
  const int tx = tid & 15, ty = tid >> 4;
  const int m0 = blockIdx.y*64, n0 = blockIdx.x*64;
  if (tid < 64) rowid[tid] = ids[m0 + tid];
  __syncthreads();
  float acc[4][4] = {};
  for (int k0 = 0; k0 < EE; k0 += 16) {
    for (int idx = tid; idx < 1024; idx += 256) {
      int r = idx >> 4, kk = idx & 15;
      int k = k0 + kk;
      As[kk][r] = (k < EE) ? emb[(size_t)rowid[r]*EE + k] : 0.f;
      Bs[kk][r] = (k < EE) ? wih[(size_t)(n0+r)*EE + k] : 0.f;
    }
    __syncthreads();
    #pragma unroll
    for (int kk=0;kk<16;kk++){
      float4 a = *reinterpret_cast<const float4*>(&As[kk][ty*4]);
      float4 b = *reinterpret_cast<const float4*>(&Bs[kk][tx*4]);
      acc[0][0]=fmaf(a.x,b.x,acc[0][0]); acc[0][1]=fmaf(a.x,b.y,acc[0][1]);
      acc[0][2]=fmaf(a.x,b.z,acc[0][2]); acc[0][3]=fmaf(a.x,b.w,acc[0][3]);
      acc[1][0]=fmaf(a.y,b.x,acc[1][0]); acc[1][1]=fmaf(a.y,b.y,acc[1][1]);
      acc[1][2]=fmaf(a.y,b.z,acc[1][2]); acc[1][3]=fmaf(a.y,b.w,acc[1][3]);
      acc[2][0]=fmaf(a.z,b.x,acc[2][0]); acc[2][1]=fmaf(a.z,b.y,acc[2][1]);
      acc[2][2]=fmaf(a.z,b.z,acc[2][2]); acc[2][3]=fmaf(a.z,b.w,acc[2][3]);
      acc[3][0]=fmaf(a.w,b.x,acc[3][0]); acc[3][1]=fmaf(a.w,b.y,acc[3][1]);
      acc[3][2]=fmaf(a.w,b.z,acc[3][2]); acc[3][3]=fmaf(a.w,b.w,acc[3][3]);
    }
    __syncthreads();
  }
  float* outp = gin + (size_t)g*LQ*G4;
  #pragma unroll
  for (int u=0;u<4;u++)
    #pragma unroll
    for (int v=0;v<4;v++)
      outp[(size_t)(m0+ty*4+u)*G4 + n0+tx*4+v] = acc[u][v];
}

// ============ 2. LSTM recurrence (R4 config — best measured, ~790us) ============
// Structural floor: 512 serial cross-CU handoffs x ~1.5us (publish->poll RTT
// via L3, intrinsic). Attacks tried and rejected: more parallelism (R1),
// LDS dedup (R2), L2 mirror (R3), scratch fix (R4, kept), batched polling
// (R5), gather fusion (R12/R13).
__global__ __launch_bounds__(512)
__attribute__((amdgpu_waves_per_eu(1,2)))
void k_lstm(
    const float* __restrict__ whh0, const float* __restrict__ whh1,
    const float* __restrict__ whh2, const float* __restrict__ whh3,
    const float* __restrict__ gin, float* __restrict__ hs, u64* __restrict__ hpub)
{
  const int g = (blockIdx.x >> 1) & 3;                       // XCD pair {2g,2g+1}
  const int b = ((blockIdx.x >> 3) << 1) | (blockIdx.x & 1); // 0..31
  const float* whh = (g==0)?whh0:(g==1)?whh1:(g==2)?whh2:whh3;
  const int tid = threadIdx.x;
  const int row_local = tid >> 3;   // 0..63
  const int chunk = tid & 7;        // 0..7
  const int gate = row_local >> 4;
  const int jj = row_local & 15;
  const int grow = gate*HH + b*JPB + jj;
  const int rot = chunk;            // rotation in float4 units (mod 16)

  // 16 named float4 registers: w{q} = Whh[grow][chunk*64 + ((q+rot)&15)*4 ..]
  const float4* wv4 = reinterpret_cast<const float4*>(whh + (size_t)grow*HH + chunk*64);
  float4 w0  = wv4[(0  + rot) & 15];
  float4 w1  = wv4[(1  + rot) & 15];
  float4 w2  = wv4[(2  + rot) & 15];
  float4 w3  = wv4[(3  + rot) & 15];
  float4 w4  = wv4[(4  + rot) & 15];
  float4 w5  = wv4[(5  + rot) & 15];
  float4 w6  = wv4[(6  + rot) & 15];
  float4 w7  = wv4[(7  + rot) & 15];
  float4 w8  = wv4[(8  + rot) & 15];
  float4 w9  = wv4[(9  + rot) & 15];
  float4 w10 = wv4[(10 + rot) & 15];
  float4 w11 = wv4[(11 + rot) & 15];
  float4 w12 = wv4[(12 + rot) & 15];
  float4 w13 = wv4[(13 + rot) & 15];
  float4 w14 = wv4[(14 + rot) & 15];
  float4 w15 = wv4[(15 + rot) & 15];

  __shared__ __align__(16) float h_lds[HH];
  __shared__ float gdot[64];

  const float* ginp = gin + (size_t)g*LQ*G4;
  float* hsg = hs + (size_t)g*LQ*HH;
  u64* hpg = hpub + (size_t)g*LQ*HH;
  const bool fwd = ((g & 1) == 0);

  // software-pipelined gate-bias: wave 0 lane l owns gate (l>>4), elem (l&15)
  float pg_cur = 0.f, pg_nxt = 0.f, creg = 0.f;
  if (tid < 64) {
    const int sidx0 = fwd ? 0 : (LQ-1);
    pg_cur = ginp[(size_t)sidx0*G4 + (size_t)(tid>>4)*HH + b*JPB + (tid&15)];
  }

  for (int s=0; s<LQ; ++s) {
    const int sidx = fwd ? s : (LQ-1-s);
    if (s == 0) {
      h_lds[tid] = 0.f;
      __syncthreads();
    } else {
      const int hidx = fwd ? (s-1) : (LQ-s);
      const u64 want = (u64)(u32)(hidx + 1);
      const u64* hp = hpg + (size_t)hidx*HH + tid;
      u64 v = __hip_atomic_load(hp, __ATOMIC_RELAXED, __HIP_MEMORY_SCOPE_AGENT);
      while ((v >> 32) != want) {
        v = __hip_atomic_load(hp, __ATOMIC_RELAXED, __HIP_MEMORY_SCOPE_AGENT);
      }
      h_lds[tid] = __uint_as_float((u32)v);
      __syncthreads();
    }
    // conflict-free rotated matvec, weights in VGPRs
    float p0=0.f, p1=0.f, p2=0.f, p3=0.f;
    {
      const float4* hld4 = reinterpret_cast<const float4*>(h_lds) + (chunk << 4);
      #define MSTEP(q, pp) { float4 hh = hld4[((q)+rot)&15]; \
        pp = fmaf(w##q.x, hh.x, pp); pp = fmaf(w##q.y, hh.y, pp); \
        pp = fmaf(w##q.z, hh.z, pp); pp = fmaf(w##q.w, hh.w, pp); }
      MSTEP(0,p0)  MSTEP(1,p1)  MSTEP(2,p2)  MSTEP(3,p3)
      MSTEP(4,p0)  MSTEP(5,p1)  MSTEP(6,p2)  MSTEP(7,p3)
      MSTEP(8,p0)  MSTEP(9,p1)  MSTEP(10,p2) MSTEP(11,p3)
      MSTEP(12,p0) MSTEP(13,p1) MSTEP(14,p2) MSTEP(15,p3)
      #undef MSTEP
    }
    // issue next step's gate-bias prefetch (consumed next iteration's tail)
    if (tid < 64) {
      const int snx = (s+1 < LQ) ? (s+1) : s;
      const int sidxn = fwd ? snx : (LQ-1-snx);
      pg_nxt = ginp[(size_t)sidxn*G4 + (size_t)(tid>>4)*HH + b*JPB + (tid&15)];
    }
    float partial = (p0 + p1) + (p2 + p3);
    partial += __shfl_xor(partial, 1);
    partial += __shfl_xor(partial, 2);
    partial += __shfl_xor(partial, 4);
    if (chunk == 0) gdot[row_local] = partial;
    __syncthreads();
    // parallel gate tail: wave 0 lane l handles gate (l>>4), elem (l&15)
    if (tid < 64) {
      float x = gdot[tid] + pg_cur;
      const int gt = tid >> 4;
      float t = (gt == 2) ? 2.f*x : x;
      t = fminf(fmaxf(t, -30.f), 30.f);
      float sg = 1.f/(1.f + __expf(-t));
      float y = (gt == 2) ? 2.f*sg - 1.f : sg;     // tanh = 2*sigmoid(2x)-1
      float vf = __shfl_down(y, 16);
      float vg = __shfl_down(y, 32);
      float vo = __shfl_down(y, 48);
      if (tid < 16) {
        float c = vf*creg + y*vg;
        creg = c;
        float tc = fminf(fmaxf(2.f*c, -30.f), 30.f);
        float th = 2.f/(1.f + __expf(-tc)) - 1.f;
        float h = vo*th;
        const int j = b*JPB + tid;
        u64 pack = ((u64)(u32)(sidx + 1) << 32) | (u64)__float_as_uint(h);
        __hip_atomic_store(hpg + (size_t)sidx*HH + j, pack,
                           __ATOMIC_RELAXED, __HIP_MEMORY_SCOPE_AGENT);
        hsg[(size_t)sidx*HH + j] = h;
      }
      pg_cur = pg_nxt;
    }
  }
}

// ============ 3. norms — wave-parallel, no barriers in k-loop ============
__global__ __launch_bounds__(256) void k_norms(
    const float* __restrict__ hs, const float* __restrict__ W3, const float* __restrict__ W4,
    float* __restrict__ nrm, float* __restrict__ np_)
{
  const int l = blockIdx.x;
  const int which = blockIdx.y;  // 0:q1p/W3 1:q2p/W3 2:q1n/W4 3:q2n/W4
  const int hsidx = (which==0)?0:(which==1)?2:(which==2)?1:3;
  const float* P = hs + (size_t)hsidx*LQ*HH + (size_t)l*HH;
  const float* Wt = (which < 2) ? W3 : W4;
  const int tid = threadIdx.x;
  const int w = tid >> 6, ln = tid & 63;
  __shared__ float p[HH];
  p[tid] = P[tid]; p[tid+256] = P[tid+256];
  __syncthreads();
  if (w == 0) {
    float v = 0.f;
    #pragma unroll
    for (int q=0;q<8;q++){ float x = p[ln+64*q]; v = fmaf(x,x,v); }
    #pragma unroll
    for (int o=32;o>0;o>>=1) v += __shfl_xor(v,o);
    if (ln==0) np_[which*LQ + l] = fmaxf(sqrtf(v), EPSF);
  }
  for (int k=w; k<WW; k+=4){
    const float* wk = Wt + (size_t)k*HH;
    float v = 0.f;
    #pragma unroll
    for (int q=0;q<8;q++){
      int e = ln + 64*q;
      float a = p[e]*wk[e];
      v = fmaf(a,a,v);
    }
    #pragma unroll
    for (int o=32;o>0;o>>=1) v += __shfl_xor(v,o);
    if (ln==0) nrm[(size_t)which*LQ*WW + (size_t)l*WW + k] = fmaxf(sqrtf(v), EPSF);
  }
}

// ============ 4. alpha = cos_pair (tiled NT GEMM, float4 LDS reads) ============
__global__ __launch_bounds__(256) void k_alpha(
    const float* __restrict__ hs, const float* __restrict__ np_, float* __restrict__ alpha)
{
  const int z = blockIdx.z;
  const float* A = hs + (size_t)(z?1:0)*LQ*HH;
  const float* B = hs + (size_t)(z?3:2)*LQ*HH;
  const float* nai = np_ + (z?2:0)*LQ;
  const float* nbj = np_ + (z?3:1)*LQ;
  float* outp = alpha + (size_t)z*LQ*LQ;
  __shared__ __align__(16) float As[16][68], Bs[16][68];
  const int tid = threadIdx.x;
  const int tx = tid & 15, ty = tid >> 4;
  const int i0 = blockIdx.y*64, j0 = blockIdx.x*64;
  float acc[4][4] = {};
  for (int k0=0;k0<HH;k0+=16){
    for (int idx=tid; idx<1024; idx+=256){
      int r = idx>>4, kk = idx&15;
      As[kk][r] = A[(size_t)(i0+r)*HH + k0+kk];
      Bs[kk][r] = B[(size_t)(j0+r)*HH + k0+kk];
    }
    __syncthreads();
    #pragma unroll
    for (int kk=0;kk<16;kk++){
      float4 a = *reinterpret_cast<const float4*>(&As[kk][ty*4]);
      float4 b = *reinterpret_cast<const float4*>(&Bs[kk][tx*4]);
      acc[0][0]=fmaf(a.x,b.x,acc[0][0]); acc[0][1]=fmaf(a.x,b.y,acc[0][1]);
      acc[0][2]=fmaf(a.x,b.z,acc[0][2]); acc[0][3]=fmaf(a.x,b.w,acc[0][3]);
      acc[1][0]=fmaf(a.y,b.x,acc[1][0]); acc[1][1]=fmaf(a.y,b.y,acc[1][1]);
      acc[1][2]=fmaf(a.y,b.z,acc[1][2]); acc[1][3]=fmaf(a.y,b.w,acc[1][3]);
      acc[2][0]=fmaf(a.z,b.x,acc[2][0]); acc[2][1]=fmaf(a.z,b.y,acc[2][1]);
      acc[2][2]=fmaf(a.z,b.z,acc[2][2]); acc[2][3]=fmaf(a.z,b.w,acc[2][3]);
      acc[3][0]=fmaf(a.w,b.x,acc[3][0]); acc[3][1]=fmaf(a.w,b.y,acc[3][1]);
      acc[3][2]=fmaf(a.w,b.z,acc[3][2]); acc[3][3]=fmaf(a.w,b.w,acc[3][3]);
    }
    __syncthreads();
  }
  #pragma unroll
  for (int u=0;u<4;u++){
    float ina = 1.f/nai[i0+ty*4+u];
    #pragma unroll
    for (int v=0;v<4;v++)
      outp[(size_t)(i0+ty*4+u)*LQ + j0+tx*4+v] = acc[u][v]*ina/nbj[j0+tx*4+v];
  }
}

// ============ 5. attention (tiled NN GEMM, rowsum fused, float4 LDS reads) ============
__global__ __launch_bounds__(256) void k_att(
    const float* __restrict__ alpha, const float* __restrict__ hs,
    float* __restrict__ att)
{
  const int z = blockIdx.z;
  const float* A = alpha + (size_t)z*LQ*LQ;
  const float* B = hs + (size_t)(z?3:2)*LQ*HH;
  float* outp = att + (size_t)z*LQ*HH;
  __shared__ __align__(16) float As[16][68], Bs[16][68];
  const int tid = threadIdx.x;
  const int tx = tid & 15, ty = tid >> 4;
  const int i0 = blockIdx.y*64, h0 = blockIdx.x*64;
  float acc[4][4] = {};
  float rsum[4] = {};
  for (int j0=0;j0<LQ;j0+=16){
    for (int idx=tid; idx<1024; idx+=256){
      int r = idx>>4, kk = idx&15;
      As[kk][r] = A[(size_t)(i0+r)*LQ + j0+kk];
    }
    for (int idx=tid; idx<1024; idx+=256){
      int jjr = idx>>6, hh = idx&63;
      Bs[jjr][hh] = B[(size_t)(j0+jjr)*HH + h0+hh];
    }
    __syncthreads();
    #pragma unroll
    for (int kk=0;kk<16;kk++){
      float4 a = *reinterpret_cast<const float4*>(&As[kk][ty*4]);
      float4 b = *reinterpret_cast<const float4*>(&Bs[kk][tx*4]);
      rsum[0]+=a.x; rsum[1]+=a.y; rsum[2]+=a.z; rsum[3]+=a.w;
      acc[0][0]=fmaf(a.x,b.x,acc[0][0]); acc[0][1]=fmaf(a.x,b.y,acc[0][1]);
      acc[0][2]=fmaf(a.x,b.z,acc[0][2]); acc[0][3]=fmaf(a.x,b.w,acc[0][3]);
      acc[1][0]=fmaf(a.y,b.x,acc[1][0]); acc[1][1]=fmaf(a.y,b.y,acc[1][1]);
      acc[1][2]=fmaf(a.y,b.z,acc[1][2]); acc[1][3]=fmaf(a.y,b.w,acc[1][3]);
      acc[2][0]=fmaf(a.z,b.x,acc[2][0]); acc[2][1]=fmaf(a.z,b.y,acc[2][1]);
      acc[2][2]=fmaf(a.z,b.z,acc[2][2]); acc[2][3]=fmaf(a.z,b.w,acc[2][3]);
      acc[3][0]=fmaf(a.w,b.x,acc[3][0]); acc[3][1]=fmaf(a.w,b.y,acc[3][1]);
      acc[3][2]=fmaf(a.w,b.z,acc[3][2]); acc[3][3]=fmaf(a.w,b.w,acc[3][3]);
    }
    __syncthreads();
  }
  #pragma unroll
  for (int u=0;u<4;u++){
    float inv = 1.f/rsum[u];
    #pragma unroll
    for (int v=0;v<4;v++)
      outp[(size_t)(i0+ty*4+u)*HH + h0+tx*4+v] = acc[u][v]*inv;
  }
}

// ============ 6. fused wcos_rows — wave-parallel, no barriers in k-loop ============
__global__ __launch_bounds__(256) void k_wcos(
    const float* __restrict__ hs, const float* __restrict__ att,
    const float* __restrict__ W1, const float* __restrict__ W2, const float* __restrict__ W5,
    float* __restrict__ outp)
{
  const int l = blockIdx.x;
  const int which = blockIdx.y;
  const int tid = threadIdx.x;
  const float* a; const float* c; const float* Wt; int m;
  switch (which) {
    case 0:  a = hs + (size_t)0*LQ*HH + (size_t)l*HH; c = hs + (size_t)2*LQ*HH + (size_t)(LQ-1)*HH; Wt = W1; m = 0; break;
    case 1:  a = hs + (size_t)1*LQ*HH + (size_t)l*HH; c = hs + (size_t)3*LQ*HH;                     Wt = W2; m = 1; break;
    case 2:  a = hs + (size_t)0*LQ*HH + (size_t)l*HH; c = att + (size_t)0*LQ*HH + (size_t)l*HH;     Wt = W5; m = 4; break;
    default: a = hs + (size_t)1*LQ*HH + (size_t)l*HH; c = att + (size_t)1*LQ*HH + (size_t)l*HH;     Wt = W5; m = 5; break;
  }
  __shared__ float av[HH], cv[HH];
  const int w = tid >> 6, ln = tid & 63;
  av[tid]=a[tid]; av[tid+256]=a[tid+256];
  cv[tid]=c[tid]; cv[tid+256]=c[tid+256];
  __syncthreads();
  for (int k=w; k<WW; k+=4){
    const float* wk = Wt + (size_t)k*HH;
    float num=0.f, na=0.f, nc=0.f;
    #pragma unroll
    for (int q=0;q<8;q++){
      int e = ln + 64*q;
      float w1 = wk[e];
      float aw = av[e]*w1;
      float cw = cv[e]*w1;
      num = fmaf(aw,cw,num);
      na  = fmaf(aw,aw,na);
      nc  = fmaf(cw,cw,nc);
    }
    #pragma unroll
    for (int o=32;o>0;o>>=1){
      num += __shfl_xor(num,o);
      na  += __shfl_xor(na,o);
      nc  += __shfl_xor(nc,o);
    }
    if (ln==0){
      float d = fmaxf(sqrtf(na),EPSF)*fmaxf(sqrtf(nc),EPSF);
      outp[((size_t)m*LQ + l)*WW + k] = num/d;
    }
  }
}

// ============ 7. pair_max v2 — weighted outer-product form (R8 proven) ============
__global__ __launch_bounds__(256) void k_pairmax(
    const float* __restrict__ hs, const float* __restrict__ W3, const float* __restrict__ W4,
    const float* __restrict__ nrm, float* __restrict__ pm_part)
{
  const int it = blockIdx.x;        // 0..7  (64-row i tile)
  const int jt = blockIdx.y;        // 0..15 (32-col j tile)
  const int z  = blockIdx.z;        // mm*2 + kh
  const int mm = z >> 1, kh = z & 1;
  const int k0 = kh*10;
  const float* A = hs + (size_t)(mm?1:0)*LQ*HH;
  const float* B = hs + (size_t)(mm?3:2)*LQ*HH;
  const float* Wt = mm ? W4 : W3;
  const float* nb = nrm + (size_t)(mm?3:1)*LQ*WW;
  const int tid = threadIdx.x;
  const int tx = tid & 31;          // j within tile
  const int ty = tid >> 5;          // i-group (8 rows each)
  const int i0 = it*64;
  const int j  = jt*32 + tx;

  __shared__ __align__(16) float As[64][128];
  __shared__ __align__(16) float Bs[32][132];
  __shared__ __align__(16) float Ws[10][128];

  float acc[8][10];
  #pragma unroll
  for (int r=0;r<8;r++)
    #pragma unroll
    for (int q=0;q<10;q++) acc[r][q]=0.f;

  for (int hc=0; hc<4; ++hc){
    const int hbase = hc*128;
    for (int idx=tid; idx<2048; idx+=256){
      int row = idx >> 5, c4 = idx & 31;
      *reinterpret_cast<float4*>(&As[row][c4*4]) =
        *reinterpret_cast<const float4*>(&A[(size_t)(i0+row)*HH + hbase + c4*4]);
    }
    for (int idx=tid; idx<1024; idx+=256){
      int row = idx >> 5, c4 = idx & 31;
      *reinterpret_cast<float4*>(&Bs[row][c4*4]) =
        *reinterpret_cast<const float4*>(&B[(size_t)(jt*32+row)*HH + hbase + c4*4]);
    }
    for (int idx=tid; idx<1280; idx+=256){
      int kk = idx >> 7, cc = idx & 127;
      float wv = Wt[(size_t)(k0+kk)*HH + hbase + cc];
      Ws[kk][cc] = wv*wv;
    }
    __syncthreads();
    #pragma unroll 2
    for (int h4=0; h4<32; ++h4){
      float4 b = *reinterpret_cast<const float4*>(&Bs[tx][h4*4]);
      float4 sa[8];
      #pragma unroll
      for (int r=0;r<8;r++){
        float4 a = *reinterpret_cast<const float4*>(&As[ty*8+r][h4*4]);
        sa[r].x = a.x*b.x; sa[r].y = a.y*b.y;
        sa[r].z = a.z*b.z; sa[r].w = a.w*b.w;
      }
      #pragma unroll
      for (int q=0;q<10;q++){
        float4 w = *reinterpret_cast<const float4*>(&Ws[q][h4*4]);
        #pragma unroll
        for (int r=0;r<8;r++){
          acc[r][q] = fmaf(sa[r].x, w.x, acc[r][q]);
          acc[r][q] = fmaf(sa[r].y, w.y, acc[r][q]);
          acc[r][q] = fmaf(sa[r].z, w.z, acc[r][q]);
          acc[r][q] = fmaf(sa[r].w, w.w, acc[r][q]);
        }
      }
    }
    __syncthreads();
  }

  // epilogue: scale by 1/nb[j][k], max over the 32 j's (lane-reduce), write partials
  float nbv[10];
  #pragma unroll
  for (int q=0;q<10;q++) nbv[q] = 1.f / nb[(size_t)j*WW + k0 + q];
  #pragma unroll
  for (int r=0;r<8;r++){
    #pragma unroll
    for (int q=0;q<10;q++){
      float v = acc[r][q] * nbv[q];
      #pragma unroll
      for (int o=1;o<32;o<<=1) v = fmaxf(v, __shfl_xor(v, o, 32));
      if (tx==0)
        pm_part[((((size_t)z*8 + it)*16 + jt)*64 + (ty*8+r))*10 + q] = v;
    }
  }
}

// ============ 8. pair_max finish: reduce 16 jt partials, divide by na ============
__global__ __launch_bounds__(256) void k_pmfin(
    const float* __restrict__ pm_part, const float* __restrict__ nrm,
    float* __restrict__ outp)
{
  const int idx = blockIdx.x*256 + threadIdx.x;   // 0..20479
  if (idx >= 2*LQ*WW) return;
  const int mm = idx / (LQ*WW);
  const int rem = idx - mm*LQ*WW;
  const int i = rem / WW, k = rem % WW;
  const int it = i >> 6, il = i & 63;
  const int kh = k / 10, kl = k % 10;
  const int z = mm*2 + kh;
  float v = -3.4e38f;
  #pragma unroll
  for (int jt=0; jt<16; ++jt)
    v = fmaxf(v, pm_part[((((size_t)z*8 + it)*16 + jt)*64 + il)*10 + kl]);
  const float* na = nrm + (size_t)(mm?2:0)*LQ*WW;
  outp[((size_t)(mm+2)*LQ + i)*WW + k] = v / na[(size_t)i*WW + k];
}

extern "C" void kernel_launch(void* const* d_in, const int* in_sizes, int n_in,
                              void* d_out, int out_size, void* d_ws, size_t ws_size,
                              hipStream_t stream)
{
  float* outp = (float*)d_out;

  float code = 0.f;
  if (n_in != 19)                    code = 101.f;
  else if (in_sizes[0]  != 512)      code = 102.f;
  else if (in_sizes[4]  != 9000000)  code = 104.f;
  else if (in_sizes[6]  != 1048576)  code = 106.f;
  else if (out_size     != 61440)    code = 108.f;
  else if (ws_size      < WS_NEEDED) code = 109.f;
  if (code != 0.f) {
    k_sentinel<<<12, 256, 0, stream>>>(outp, code);
    return;
  }

  const int* q1_ids = (const int*)d_in[0];
  const int* q2_ids = (const int*)d_in[1];
  const float* emb      = (const float*)d_in[4];
  const float* q1_wih_f = (const float*)d_in[5];
  const float* q1_whh_f = (const float*)d_in[6];
  const float* q1_wih_b = (const float*)d_in[7];
  const float* q1_whh_b = (const float*)d_in[8];
  const float* q2_wih_f = (const float*)d_in[9];
  const float* q2_whh_f = (const float*)d_in[10];
  const float* q2_wih_b = (const float*)d_in[11];
  const float* q2_whh_b = (const float*)d_in[12];
  const float* W1 = (const float*)d_in[13];
  const float* W2 = (const float*)d_in[14];
  const float* W3 = (const float*)d_in[15];
  const float* W4 = (const float*)d_in[16];
  const float* W5 = (const float*)d_in[17];
  float* ws = (float*)d_ws;

  float* gin   = ws + OFF_GIN;
  float* hsv   = ws + OFF_HS;
  u64*   hpub  = (u64*)(ws + OFF_HPUB);
  float* alpha = ws + OFF_ALPHA;
  float* att   = ws + OFF_ATT;
  float* nrm   = ws + OFF_NRM;
  float* np_   = ws + OFF_NP;
  float* pmp   = ws + OFF_PMP;

  k_gather_gemm<<<dim3(32,8,4), 256, 0, stream>>>(emb, q1_ids, q2_ids,
      q1_wih_f, q1_wih_b, q2_wih_f, q2_wih_b, gin);
  k_lstm<<<dim3(4*RB), 512, 0, stream>>>(q1_whh_f, q1_whh_b, q2_whh_f, q2_whh_b,
      gin, hsv, hpub);
  k_norms<<<dim3(LQ,4), 256, 0, stream>>>(hsv, W3, W4, nrm, np_);
  k_alpha<<<dim3(8,8,2), 256, 0, stream>>>(hsv, np_, alpha);
  k_att<<<dim3(8,8,2), 256, 0, stream>>>(alpha, hsv, att);
  k_wcos<<<dim3(LQ,4), 256, 0, stream>>>(hsv, att, W1, W2, W5, outp);
  k_pairmax<<<dim3(8,16,4), 256, 0, stream>>>(hsv, W3, W4, nrm, pmp);
  k_pmfin<<<dim3(80), 256, 0, stream>>>(pmp, nrm, outp);
}